// Round 3
// baseline (728.937 us; speedup 1.0000x reference)
//
#include <hip/hip_runtime.h>

#define IN_DIM 4096
#define N_SOMA 16384
#define N_NEURONS 1024
#define BATCH 256
#define NEG_SLOPE 0.1f

typedef float f32x4 __attribute__((ext_vector_type(4)));

// ---------------------------------------------------------------------------
// Kernel 1: transpose x [BATCH][IN_DIM] -> xT [IN_DIM][BATCH]
// ---------------------------------------------------------------------------
__global__ __launch_bounds__(256) void transpose_x_kernel(
    const float* __restrict__ x, float* __restrict__ xT) {
    __shared__ float tile[64][65];
    const int i0 = blockIdx.x * 64;
    const int b0 = blockIdx.y * 64;
    const int lane = threadIdx.x & 63;
    const int grp  = threadIdx.x >> 6;

#pragma unroll
    for (int r = 0; r < 16; ++r) {
        const int b_local = grp * 16 + r;
        tile[b_local][lane] = x[(size_t)(b0 + b_local) * IN_DIM + i0 + lane];
    }
    __syncthreads();
#pragma unroll
    for (int r = 0; r < 16; ++r) {
        const int i_local = grp * 16 + r;
        xT[(size_t)(i0 + i_local) * BATCH + b0 + lane] = tile[lane][i_local];
    }
}

// ---------------------------------------------------------------------------
// Kernel 2: fully fused. One block per neuron (16 dendrite rows, 256 KB of
// dW). Software pipeline over 4 groups of 4 rows:
//   issue group g+1's 16 nontemporal HBM loads -> compute group g's
//   gather-FMAs from L2-resident xT -> ballot-compact group g+1 into LDS.
// HBM streaming never waits on the gather phase. No global intermediates.
// ---------------------------------------------------------------------------
__global__ __launch_bounds__(256, 4) void fused_kernel(
    const float* __restrict__ dW, const float* __restrict__ db,
    const float* __restrict__ sW, const float* __restrict__ sb,
    const float* __restrict__ xT, float* __restrict__ out) {
    const int bid = blockIdx.x;
    // XCD-chunked swizzle: 128 consecutive neurons per XCD -> output-line
    // write merging and xT locality within one L2.
    const int n = (bid & 7) * (N_NEURONS / 8) + (bid >> 3);
    const int t = threadIdx.x;
    const int wave = t >> 6;
    const int lane = t & 63;
    const unsigned long long lt = (1ull << lane) - 1ull;

    __shared__ int   s_idx[16][32];   // pre-scaled: idx * BATCH
    __shared__ float s_w[16][32];
    __shared__ float s_sw[16];
    __shared__ float s_db[16];

    if (t < 16) {
        s_sw[t] = sW[(size_t)n * N_SOMA + n * 16 + t];
        s_db[t] = db[n * 16 + t];
    }

    f32x4 v[16];

#define LOAD_ROW(RL) do {                                                     \
        const f32x4* row4 = reinterpret_cast<const f32x4*>(                   \
            dW + (size_t)(n * 16 + (RL)) * IN_DIM);                           \
        _Pragma("unroll")                                                     \
        for (int k = 0; k < 16; ++k)                                          \
            v[k] = __builtin_nontemporal_load(row4 + k * 64 + lane);          \
    } while (0)

    // Deterministic in-wave compaction: element order = ascending global
    // index ((k*64+lane)*4 + c) = lane-major within chunk, chunk-major.
#define COMPACT_ROW(RL) do {                                                  \
        int base = 0;                                                         \
        _Pragma("unroll")                                                     \
        for (int k = 0; k < 16; ++k) {                                        \
            float e[4] = {v[k].x, v[k].y, v[k].z, v[k].w};                    \
            unsigned long long m[4];                                          \
            _Pragma("unroll")                                                 \
            for (int c = 0; c < 4; ++c) m[c] = __ballot(e[c] != 0.f);         \
            int below = 0;                                                    \
            _Pragma("unroll")                                                 \
            for (int c = 0; c < 4; ++c) below += __popcll(m[c] & lt);         \
            int myprev = 0;                                                   \
            _Pragma("unroll")                                                 \
            for (int c = 0; c < 4; ++c) {                                     \
                if (e[c] != 0.f) {                                            \
                    const int pos = base + below + myprev;                    \
                    if (pos < 32) {                                           \
                        s_idx[RL][pos] = (((k * 64 + lane) << 2) + c) << 8;   \
                        s_w[RL][pos] = e[c];                                  \
                    }                                                         \
                    ++myprev;                                                 \
                }                                                             \
            }                                                                 \
            _Pragma("unroll")                                                 \
            for (int c = 0; c < 4; ++c) base += __popcll(m[c]);               \
        }                                                                     \
    } while (0)

#define COMPUTE_ROW(RL) do {                                                  \
        float dacc = s_db[RL];                                                \
        _Pragma("unroll")                                                     \
        for (int j = 0; j < 32; ++j)                                          \
            dacc = fmaf(s_w[RL][j], xT[(size_t)s_idx[RL][j] + t], dacc);      \
        dacc = (dacc >= 0.f) ? dacc : NEG_SLOPE * dacc;                       \
        sacc = fmaf(s_sw[RL], dacc, sacc);                                    \
    } while (0)

    // Prologue: group 0 (rows 0..3, one per wave).
    LOAD_ROW(wave);
    COMPACT_ROW(wave);
    __syncthreads();

    float sacc = sb[n];
    for (int g = 0; g < 4; ++g) {
        if (g < 3) LOAD_ROW((g + 1) * 4 + wave);   // HBM loads in flight
        COMPUTE_ROW(4 * g + 0);                     // L2 gathers + FMA
        COMPUTE_ROW(4 * g + 1);
        COMPUTE_ROW(4 * g + 2);
        COMPUTE_ROW(4 * g + 3);
        if (g < 3) COMPACT_ROW((g + 1) * 4 + wave); // waits vmcnt, writes LDS
        __syncthreads();
    }
    sacc = (sacc >= 0.f) ? sacc : NEG_SLOPE * sacc;
    out[(size_t)t * N_NEURONS + n] = sacc;

#undef LOAD_ROW
#undef COMPACT_ROW
#undef COMPUTE_ROW
}

// ---------------------------------------------------------------------------
extern "C" void kernel_launch(void* const* d_in, const int* in_sizes, int n_in,
                              void* d_out, int out_size, void* d_ws, size_t ws_size,
                              hipStream_t stream) {
    const float* x  = (const float*)d_in[0];  // [256][4096]
    const float* dW = (const float*)d_in[1];  // [16384][4096] (pre-masked)
    const float* db = (const float*)d_in[2];  // [16384]
    const float* sW = (const float*)d_in[3];  // [1024][16384] (pre-masked)
    const float* sb = (const float*)d_in[4];  // [1024]
    float* out = (float*)d_out;               // [256][1024]

    float* xT = (float*)d_ws;                 // [4096][256]  4 MB

    transpose_x_kernel<<<dim3(IN_DIM / 64, BATCH / 64), 256, 0, stream>>>(x, xT);
    fused_kernel<<<N_NEURONS, 256, 0, stream>>>(dW, db, sW, sb, xT, out);
}

// Round 4
// 84.148 us; speedup vs baseline: 8.6625x; 8.6625x over previous
//
#include <hip/hip_runtime.h>

#define IN_DIM 4096
#define N_SOMA 16384
#define N_NEURONS 1024
#define BATCH 256
#define NEG_SLOPE 0.1f

typedef float f32x4 __attribute__((ext_vector_type(4)));

// ---------------------------------------------------------------------------
// Kernel 1: transpose x [BATCH][IN_DIM] -> xT [IN_DIM][BATCH]
// ---------------------------------------------------------------------------
__global__ __launch_bounds__(256) void transpose_x_kernel(
    const float* __restrict__ x, float* __restrict__ xT) {
    __shared__ float tile[64][65];
    const int i0 = blockIdx.x * 64;
    const int b0 = blockIdx.y * 64;
    const int lane = threadIdx.x & 63;
    const int grp  = threadIdx.x >> 6;

#pragma unroll
    for (int r = 0; r < 16; ++r) {
        const int b_local = grp * 16 + r;
        tile[b_local][lane] = x[(size_t)(b0 + b_local) * IN_DIM + i0 + lane];
    }
    __syncthreads();
#pragma unroll
    for (int r = 0; r < 16; ++r) {
        const int i_local = grp * 16 + r;
        xT[(size_t)(i0 + i_local) * BATCH + b0 + lane] = tile[lane][i_local];
    }
}

// ---------------------------------------------------------------------------
// Kernel 2: fully fused, NO in-register pipeline (Round-3 spilled).
// One block per neuron. Stage phase: each wave loads+compacts 4 rows
// back-to-back (v[] live only within one row iteration -> no spill).
// One barrier. Compute phase: all waves, 16 rows x 32 L2 gathers, fully
// unrolled. Cross-block TLP (4 blocks/CU) overlaps HBM streaming of some
// blocks with L2 gathers of others.
// ---------------------------------------------------------------------------
__global__ __launch_bounds__(256, 4) void fused_kernel(
    const float* __restrict__ dW, const float* __restrict__ db,
    const float* __restrict__ sW, const float* __restrict__ sb,
    const float* __restrict__ xT, float* __restrict__ out) {
    const int bid = blockIdx.x;
    // XCD-chunked swizzle: 128 consecutive neurons per XCD -> write merging
    // and xT locality within one L2.
    const int n = (bid & 7) * (N_NEURONS / 8) + (bid >> 3);
    const int t = threadIdx.x;
    const int wave = t >> 6;
    const int lane = t & 63;
    const unsigned long long lt = (1ull << lane) - 1ull;

    __shared__ int   s_idx[16][32];   // pre-scaled: idx * BATCH
    __shared__ float s_w[16][32];
    __shared__ float s_sw[16];
    __shared__ float s_db[16];

    if (t < 16) {
        s_sw[t] = sW[(size_t)n * N_SOMA + n * 16 + t];
        s_db[t] = db[n * 16 + t];
    }

    // ---- Stage: wave w compacts rows {w, 4+w, 8+w, 12+w} ----
    for (int rr = 0; rr < 4; ++rr) {
        const int r = rr * 4 + wave;
        const f32x4* row4 = reinterpret_cast<const f32x4*>(
            dW + (size_t)(n * 16 + r) * IN_DIM);
        f32x4 v[16];
#pragma unroll
        for (int k = 0; k < 16; ++k)
            v[k] = __builtin_nontemporal_load(row4 + k * 64 + lane);

        // Deterministic compaction: order = ascending global index
        // (k*256 + lane*4 + c).
        int base = 0;
#pragma unroll
        for (int k = 0; k < 16; ++k) {
            float e[4] = {v[k].x, v[k].y, v[k].z, v[k].w};
            unsigned long long m[4];
#pragma unroll
            for (int c = 0; c < 4; ++c) m[c] = __ballot(e[c] != 0.f);
            int below = 0;
#pragma unroll
            for (int c = 0; c < 4; ++c) below += __popcll(m[c] & lt);
            int myprev = 0;
#pragma unroll
            for (int c = 0; c < 4; ++c) {
                if (m[c]) {
                    if (e[c] != 0.f) {
                        const int pos = base + below + myprev;
                        if (pos < 32) {
                            s_idx[r][pos] = (((k * 64 + lane) << 2) + c) << 8;
                            s_w[r][pos] = e[c];
                        }
                        ++myprev;
                    }
                }
            }
#pragma unroll
            for (int c = 0; c < 4; ++c) base += __popcll(m[c]);
        }
    }
    __syncthreads();

    // ---- Compute: thread t = batch column; 512 independent L2 gathers ----
    float sacc = sb[n];
#pragma unroll
    for (int r = 0; r < 16; ++r) {
        float dacc = s_db[r];
#pragma unroll
        for (int j = 0; j < 32; ++j)
            dacc = fmaf(s_w[r][j], xT[(size_t)s_idx[r][j] + t], dacc);
        dacc = (dacc >= 0.f) ? dacc : NEG_SLOPE * dacc;
        sacc = fmaf(s_sw[r], dacc, sacc);
    }
    sacc = (sacc >= 0.f) ? sacc : NEG_SLOPE * sacc;
    out[(size_t)t * N_NEURONS + n] = sacc;
}

// ---------------------------------------------------------------------------
extern "C" void kernel_launch(void* const* d_in, const int* in_sizes, int n_in,
                              void* d_out, int out_size, void* d_ws, size_t ws_size,
                              hipStream_t stream) {
    const float* x  = (const float*)d_in[0];  // [256][4096]
    const float* dW = (const float*)d_in[1];  // [16384][4096] (pre-masked)
    const float* db = (const float*)d_in[2];  // [16384]
    const float* sW = (const float*)d_in[3];  // [1024][16384] (pre-masked)
    const float* sb = (const float*)d_in[4];  // [1024]
    float* out = (float*)d_out;               // [256][1024]

    float* xT = (float*)d_ws;                 // [4096][256]  4 MB

    transpose_x_kernel<<<dim3(IN_DIM / 64, BATCH / 64), 256, 0, stream>>>(x, xT);
    fused_kernel<<<N_NEURONS, 256, 0, stream>>>(dW, db, sW, sb, xT, out);
}